// Round 2
// baseline (2026.157 us; speedup 1.0000x reference)
//
#include <hip/hip_runtime.h>
#include <hip/hip_bf16.h>

// LSTM classifier: B=64, S=2048, E=H=128, OUT=1.
// Phase A (parallel): pre[t][g][b][j] = bias[g][j] + emb[x[b,t]] . W_g[j][0:128]
// Phase B (sequential, 1 WG per batch, 256 thr): thread=(j, gate), full-k dot,
//   weights pinned in VGPRs, h broadcast from LDS (double-buffered, 1 barrier/step),
//   single shfl_xor to exchange the two gate sums.

#define LSTM_B 64
#define LSTM_E 128
#define LSTM_H 128
#define ROWW   256           // E+H, weight row width
#define TSTRIDE (2*LSTM_B*LSTM_H)   // floats per timestep in pre buffer

__device__ __forceinline__ float fast_rcp(float x) {
    return __builtin_amdgcn_rcpf(x);     // v_rcp_f32, ~1 ulp — fine vs 1e-2 threshold
}
__device__ __forceinline__ float sigmoidf_(float x) {
    return fast_rcp(1.0f + __expf(-x));
}
__device__ __forceinline__ float tanh_fast(float x) {
    float ax = fabsf(x);
    float t = __expf(-2.0f * ax);          // in (0,1], no overflow
    float r = (1.0f - t) * fast_rcp(1.0f + t);
    return copysignf(r, x);
}

// ---------------- Phase A: input projections for both gates ----------------
// grid: (t1-t0)*4 blocks; block 256 threads.
// Each block: one timestep t, 16 batch rows. thread=(g, j): 16 outputs.
__global__ __launch_bounds__(256) void lstm_phaseA(
    const int* __restrict__ x, const float* __restrict__ emb,
    const float* __restrict__ Wf, const float* __restrict__ bf,
    const float* __restrict__ Wc, const float* __restrict__ bc,
    float* __restrict__ pre, int t0, int S)
{
    __shared__ __align__(16) float emb_s[16][LSTM_E];
    __shared__ int idx_s[16];

    const int tile = blockIdx.x;
    const int t  = t0 + (tile >> 2);
    const int b0 = (tile & 3) << 4;
    const int tid = threadIdx.x;

    if (tid < 16) idx_s[tid] = x[(size_t)(b0 + tid) * S + t];
    __syncthreads();
    {   // stage 16 embedding rows (16 x 512B)
        const int r  = tid >> 4;
        const int cp = (tid & 15) << 3;
        const float* src = emb + (size_t)idx_s[r] * LSTM_E + cp;
        float4 v0 = *(const float4*)src;
        float4 v1 = *(const float4*)(src + 4);
        *(float4*)&emb_s[r][cp]     = v0;
        *(float4*)&emb_s[r][cp + 4] = v1;
    }
    __syncthreads();

    const int g = tid >> 7, j = tid & 127;
    const float* Wrow = (g ? Wc : Wf) + (size_t)j * ROWW;   // cols 0..127
    const float bias  = (g ? bc : bf)[j];

    float acc[16];
#pragma unroll
    for (int b = 0; b < 16; ++b) acc[b] = bias;

    for (int kc = 0; kc < LSTM_E; kc += 16) {
        float4 wv[4];
#pragma unroll
        for (int i = 0; i < 4; ++i) wv[i] = *(const float4*)(Wrow + kc + 4*i);
#pragma unroll
        for (int b = 0; b < 16; ++b) {
#pragma unroll
            for (int i = 0; i < 4; ++i) {
                float4 ev = *(const float4*)&emb_s[b][kc + 4*i];   // LDS broadcast
                acc[b] += ev.x*wv[i].x + ev.y*wv[i].y + ev.z*wv[i].z + ev.w*wv[i].w;
            }
        }
    }

    float* dst = pre + ((size_t)(t - t0) * 2 + g) * (LSTM_B * LSTM_H)
                     + (size_t)b0 * LSTM_H + j;
#pragma unroll
    for (int b = 0; b < 16; ++b) dst[(size_t)b * LSTM_H] = acc[b];   // coalesced in j
}

// ---------------- Phase B: the recurrence ----------------
// grid: 64 blocks (one per batch), 256 threads (4 waves).
// thread = (j = tid>>1, g = tid&1): full 128-k dot for one gate, weights in
// 128 pinned VGPRs. h reads are whole-wave broadcasts (conflict-free).
// One shfl_xor(1) swaps gate sums within the lane pair; c replicated on both.
__global__ __launch_bounds__(256, 1) void lstm_phaseB(
    const float* __restrict__ Wf, const float* __restrict__ Wc,
    const float* __restrict__ Wfc, const float* __restrict__ bfc,
    const float* __restrict__ pre, float* __restrict__ state,
    float* __restrict__ out, int t0, int t1, int S)
{
    __shared__ __align__(16) float h_s[2][LSTM_H];
    __shared__ float red_s[LSTM_H];

    const int b   = blockIdx.x;
    const int tid = threadIdx.x;
    const int g   = tid & 1;
    const int j   = tid >> 1;        // 0..127

    const float* Wrow = (g ? Wc : Wf) + (size_t)j * ROWW + LSTM_E;   // h-columns
    float4 w[32];
#pragma unroll
    for (int i = 0; i < 32; ++i) w[i] = *(const float4*)(Wrow + 4*i);
    // Pin weights in VGPRs: asm-defined values cannot be rematerialized as
    // in-loop L1 reloads (round-1 showed VGPR=52 -> compiler sank the loads).
#pragma unroll
    for (int i = 0; i < 32; ++i)
        asm volatile("" : "+v"(w[i].x), "+v"(w[i].y), "+v"(w[i].z), "+v"(w[i].w));

    float c = 0.0f;
    if (t0 == 0) {
        if (tid < LSTM_H) h_s[0][tid] = 0.0f;
    } else {
        if (tid < LSTM_H) h_s[0][tid] = state[(size_t)b * LSTM_H + tid];
        c = state[LSTM_B * LSTM_H + (size_t)b * LSTM_H + j];   // replicated read
    }

    // pre[t][g][b][j]: per-thread stream, 2-deep prefetch.
    const float* prep = pre + (size_t)g * (LSTM_B * LSTM_H)
                            + (size_t)b * LSTM_H + j;
    float p0 = prep[0];
    float p1 = (t1 - t0 > 1) ? prep[TSTRIDE] : 0.0f;
    __syncthreads();

    int cur = 0;
    for (int t = t0; t < t1; ++t) {
        float a0 = p0, a1 = 0.f, a2 = 0.f, a3 = 0.f;
        p0 = p1;
        if ((t + 2) < t1) p1 = prep[(size_t)(t + 2 - t0) * TSTRIDE];
#pragma unroll
        for (int i = 0; i < 32; ++i) {
            float4 hv = *(const float4*)&h_s[cur][4*i];   // wave-broadcast read
            a0 += hv.x * w[i].x; a1 += hv.y * w[i].y;
            a2 += hv.z * w[i].z; a3 += hv.w * w[i].w;
        }
        float a = (a0 + a1) + (a2 + a3);
        float o = __shfl_xor(a, 1, 64);
        float af = g ? o : a;            // forget-gate sum (bug-compatible: f==i==o)
        float ac = g ? a : o;            // candidate sum

        float gg = sigmoidf_(af);
        float ct = tanh_fast(ac);
        c = gg * (c + ct);               // identical on both lanes of the pair
        float hn = gg * tanh_fast(c);
        if (!g) h_s[cur ^ 1][j] = hn;
        __syncthreads();                 // single barrier per step
        cur ^= 1;
    }

    if (t1 == S) {
        if (tid < LSTM_H) red_s[tid] = h_s[cur][tid] * Wfc[tid];
        __syncthreads();
        if (tid == 0) {
            float s = bfc[0];
            for (int k = 0; k < LSTM_H; ++k) s += red_s[k];
            out[b] = sigmoidf_(s);
        }
    } else {
        if (tid < LSTM_H) state[(size_t)b * LSTM_H + tid] = h_s[cur][tid];
        if (!g) state[LSTM_B * LSTM_H + (size_t)b * LSTM_H + j] = c;
    }
}

extern "C" void kernel_launch(void* const* d_in, const int* in_sizes, int n_in,
                              void* d_out, int out_size, void* d_ws, size_t ws_size,
                              hipStream_t stream) {
    const int*   x   = (const int*)d_in[0];
    const float* emb = (const float*)d_in[1];
    const float* Wf  = (const float*)d_in[2];
    const float* bf  = (const float*)d_in[3];
    const float* Wc  = (const float*)d_in[4];
    const float* bc  = (const float*)d_in[5];
    const float* Wfc = (const float*)d_in[6];
    const float* bfc = (const float*)d_in[7];
    float* out = (float*)d_out;

    const int S = in_sizes[0] / LSTM_B;           // 2048

    float* state = (float*)d_ws;                              // h[64][128], c[64][128]
    float* pre   = state + (size_t)2 * LSTM_B * LSTM_H;       // + 64KB

    const size_t state_bytes = (size_t)2 * LSTM_B * LSTM_H * sizeof(float);
    const size_t per_t_bytes = (size_t)TSTRIDE * sizeof(float);   // 64 KB per step
    size_t avail = (ws_size > state_bytes) ? (ws_size - state_bytes) : 0;
    int CH = (int)(avail / per_t_bytes);
    if (CH > S) CH = S;
    if (CH < 1) CH = 1;   // requires ws_size >= 128KB + state

    for (int t0 = 0; t0 < S; t0 += CH) {
        const int t1 = (t0 + CH < S) ? (t0 + CH) : S;
        lstm_phaseA<<<(t1 - t0) * 4, 256, 0, stream>>>(x, emb, Wf, bf, Wc, bc,
                                                       pre, t0, S);
        lstm_phaseB<<<LSTM_B, 256, 0, stream>>>(Wf, Wc, Wfc, bfc, pre, state,
                                                out, t0, t1, S);
    }
}

// Round 3
// 1646.065 us; speedup vs baseline: 1.2309x; 1.2309x over previous
//
#include <hip/hip_runtime.h>
#include <hip/hip_bf16.h>

// LSTM classifier: B=64, S=2048, E=H=128, OUT=1.
// Phase A (parallel): pre[t][g][b][j] = bias[g][j] + emb[x[b,t]] . W_g[j][0:128]
// Phase B (sequential, 1 WG per batch, 512 thr = 8 waves):
//   thread = (j, gate, k-half): 64 weight floats in VGPRs (16 float4),
//   __launch_bounds__(512,2) caps occupancy target at 2 waves/EU -> 256 VGPR
//   budget -> allocator keeps weights resident instead of re-sinking the loads
//   (round-1 failure: default bounds targeted max occupancy, VGPR=52, L1-BW
//   bound on reloads; round-2 failure: asm pin forced scratch spills).
//   h broadcast from LDS double-buffer (2 distinct addrs/wave = free),
//   shfl_xor(1) sums k-halves, shfl_xor(2) swaps gate sums. 1 barrier/step.

#define LSTM_B 64
#define LSTM_E 128
#define LSTM_H 128
#define ROWW   256           // E+H, weight row width
#define TSTRIDE (2*LSTM_B*LSTM_H)   // floats per timestep in pre buffer

__device__ __forceinline__ float fast_rcp(float x) {
    return __builtin_amdgcn_rcpf(x);     // v_rcp_f32, ~1 ulp — fine vs 1e-2 threshold
}
__device__ __forceinline__ float sigmoidf_(float x) {
    return fast_rcp(1.0f + __expf(-x));
}
__device__ __forceinline__ float tanh_fast(float x) {
    float ax = fabsf(x);
    float t = __expf(-2.0f * ax);          // in (0,1], no overflow
    float r = (1.0f - t) * fast_rcp(1.0f + t);
    return copysignf(r, x);
}

// ---------------- Phase A: input projections for both gates ----------------
// grid: (t1-t0)*4 blocks; block 256 threads.
// Each block: one timestep t, 16 batch rows. thread=(g, j): 16 outputs.
__global__ __launch_bounds__(256) void lstm_phaseA(
    const int* __restrict__ x, const float* __restrict__ emb,
    const float* __restrict__ Wf, const float* __restrict__ bf,
    const float* __restrict__ Wc, const float* __restrict__ bc,
    float* __restrict__ pre, int t0, int S)
{
    __shared__ __align__(16) float emb_s[16][LSTM_E];
    __shared__ int idx_s[16];

    const int tile = blockIdx.x;
    const int t  = t0 + (tile >> 2);
    const int b0 = (tile & 3) << 4;
    const int tid = threadIdx.x;

    if (tid < 16) idx_s[tid] = x[(size_t)(b0 + tid) * S + t];
    __syncthreads();
    {   // stage 16 embedding rows (16 x 512B)
        const int r  = tid >> 4;
        const int cp = (tid & 15) << 3;
        const float* src = emb + (size_t)idx_s[r] * LSTM_E + cp;
        float4 v0 = *(const float4*)src;
        float4 v1 = *(const float4*)(src + 4);
        *(float4*)&emb_s[r][cp]     = v0;
        *(float4*)&emb_s[r][cp + 4] = v1;
    }
    __syncthreads();

    const int g = tid >> 7, j = tid & 127;
    const float* Wrow = (g ? Wc : Wf) + (size_t)j * ROWW;   // cols 0..127
    const float bias  = (g ? bc : bf)[j];

    float acc[16];
#pragma unroll
    for (int b = 0; b < 16; ++b) acc[b] = bias;

    for (int kc = 0; kc < LSTM_E; kc += 16) {
        float4 wv[4];
#pragma unroll
        for (int i = 0; i < 4; ++i) wv[i] = *(const float4*)(Wrow + kc + 4*i);
#pragma unroll
        for (int b = 0; b < 16; ++b) {
#pragma unroll
            for (int i = 0; i < 4; ++i) {
                float4 ev = *(const float4*)&emb_s[b][kc + 4*i];   // LDS broadcast
                acc[b] += ev.x*wv[i].x + ev.y*wv[i].y + ev.z*wv[i].z + ev.w*wv[i].w;
            }
        }
    }

    float* dst = pre + ((size_t)(t - t0) * 2 + g) * (LSTM_B * LSTM_H)
                     + (size_t)b0 * LSTM_H + j;
#pragma unroll
    for (int b = 0; b < 16; ++b) dst[(size_t)b * LSTM_H] = acc[b];   // coalesced in j
}

// ---------------- Phase B: the recurrence ----------------
// grid: 64 blocks (one per batch), 512 threads (8 waves, 2/SIMD).
// tid = (j<<2) | (g<<1) | kh : j=output row, g=gate, kh=k-half.
// 16 float4 weights per thread; h reads are 2-address wave broadcasts.
__global__ __launch_bounds__(512, 2) void lstm_phaseB(
    const float* __restrict__ Wf, const float* __restrict__ Wc,
    const float* __restrict__ Wfc, const float* __restrict__ bfc,
    const float* __restrict__ pre, float* __restrict__ state,
    float* __restrict__ out, int t0, int t1, int S)
{
    __shared__ __align__(16) float h_s[2][LSTM_H];
    __shared__ float red_s[LSTM_H];

    const int b   = blockIdx.x;
    const int tid = threadIdx.x;
    const int kh  = tid & 1;
    const int g   = (tid >> 1) & 1;
    const int j   = tid >> 2;        // 0..127

    const float* Wrow = (g ? Wc : Wf) + (size_t)j * ROWW + LSTM_E + kh * 64;
    float4 w[16];
#pragma unroll
    for (int i = 0; i < 16; ++i) w[i] = *(const float4*)(Wrow + 4*i);

    float c = 0.0f;
    if (t0 == 0) {
        if (tid < LSTM_H) h_s[0][tid] = 0.0f;
    } else {
        if (tid < LSTM_H) h_s[0][tid] = state[(size_t)b * LSTM_H + tid];
        c = state[LSTM_B * LSTM_H + (size_t)b * LSTM_H + j];   // replicated read
    }

    // pre[t][g][b][j]: one lane (kh==0) per (j,g) streams it, 2-deep prefetch.
    const float* prep = pre + (size_t)g * (LSTM_B * LSTM_H)
                            + (size_t)b * LSTM_H + j;
    float p0 = 0.f, p1 = 0.f;
    if (kh == 0) {
        p0 = prep[0];
        if (t1 - t0 > 1) p1 = prep[TSTRIDE];
    }
    __syncthreads();

    int cur = 0;
    for (int t = t0; t < t1; ++t) {
        float a0 = (kh == 0) ? p0 : 0.0f, a1 = 0.f, a2 = 0.f, a3 = 0.f;
        p0 = p1;
        if (kh == 0 && (t + 2) < t1)                 // 2-deep prefetch
            p1 = prep[(size_t)(t + 2 - t0) * TSTRIDE];

        const float* hb = &h_s[cur][kh * 64];
#pragma unroll
        for (int i = 0; i < 16; ++i) {
            float4 hv = *(const float4*)(hb + 4*i);  // 2-addr wave broadcast
            a0 += hv.x * w[i].x; a1 += hv.y * w[i].y;
            a2 += hv.z * w[i].z; a3 += hv.w * w[i].w;
        }
        float a = (a0 + a1) + (a2 + a3);
        a += __shfl_xor(a, 1, 64);       // combine k-halves -> full gate sum
        float o = __shfl_xor(a, 2, 64);  // other gate's sum
        float af = g ? o : a;            // forget/shared gate (bug-compat: f==i==o)
        float ac = g ? a : o;            // candidate

        float gg = sigmoidf_(af);
        float ct = tanh_fast(ac);
        c = gg * (c + ct);               // identical on the 4 lanes of each j
        float hn = gg * tanh_fast(c);
        if ((tid & 3) == 0) h_s[cur ^ 1][j] = hn;
        __syncthreads();                 // single barrier per step
        cur ^= 1;
    }

    if (t1 == S) {
        if (tid < LSTM_H) red_s[tid] = h_s[cur][tid] * Wfc[tid];
        __syncthreads();
        if (tid < 64) {
            float s = red_s[tid] + red_s[tid + 64];
            s += __shfl_down(s, 32, 64);
            s += __shfl_down(s, 16, 64);
            s += __shfl_down(s, 8, 64);
            s += __shfl_down(s, 4, 64);
            s += __shfl_down(s, 2, 64);
            s += __shfl_down(s, 1, 64);
            if (tid == 0) out[b] = sigmoidf_(s + bfc[0]);
        }
    } else {
        if (tid < LSTM_H) state[(size_t)b * LSTM_H + tid] = h_s[cur][tid];
        if ((tid & 3) == 0) state[LSTM_B * LSTM_H + (size_t)b * LSTM_H + j] = c;
    }
}

extern "C" void kernel_launch(void* const* d_in, const int* in_sizes, int n_in,
                              void* d_out, int out_size, void* d_ws, size_t ws_size,
                              hipStream_t stream) {
    const int*   x   = (const int*)d_in[0];
    const float* emb = (const float*)d_in[1];
    const float* Wf  = (const float*)d_in[2];
    const float* bf  = (const float*)d_in[3];
    const float* Wc  = (const float*)d_in[4];
    const float* bc  = (const float*)d_in[5];
    const float* Wfc = (const float*)d_in[6];
    const float* bfc = (const float*)d_in[7];
    float* out = (float*)d_out;

    const int S = in_sizes[0] / LSTM_B;           // 2048

    float* state = (float*)d_ws;                              // h[64][128], c[64][128]
    float* pre   = state + (size_t)2 * LSTM_B * LSTM_H;       // + 64KB

    const size_t state_bytes = (size_t)2 * LSTM_B * LSTM_H * sizeof(float);
    const size_t per_t_bytes = (size_t)TSTRIDE * sizeof(float);   // 64 KB per step
    size_t avail = (ws_size > state_bytes) ? (ws_size - state_bytes) : 0;
    int CH = (int)(avail / per_t_bytes);
    if (CH > S) CH = S;
    if (CH < 1) CH = 1;   // requires ws_size >= 128KB + state

    for (int t0 = 0; t0 < S; t0 += CH) {
        const int t1 = (t0 + CH < S) ? (t0 + CH) : S;
        lstm_phaseA<<<(t1 - t0) * 4, 256, 0, stream>>>(x, emb, Wf, bf, Wc, bc,
                                                       pre, t0, S);
        lstm_phaseB<<<LSTM_B, 512, 0, stream>>>(Wf, Wc, Wfc, bfc, pre, state,
                                                out, t0, t1, S);
    }
}

// Round 4
// 1094.966 us; speedup vs baseline: 1.8504x; 1.5033x over previous
//
#include <hip/hip_runtime.h>
#include <hip/hip_bf16.h>

// LSTM classifier: B=64, S=2048, E=H=128, OUT=1.
// Phase A (parallel): pre[t][g][b][j] = bias[g][j] + emb[x[b,t]] . W_g[j][0:128]
// Phase B (sequential, 1 WG per batch, 8 waves): per-step h-matmul via
//   mfma_f32_16x16x32_bf16, M=1 (only C-row 0 used). Weights = B-fragments,
//   fp32 split into bf16 hi+lo (2 MFMAs) -> fp32-grade accuracy; the
//   load+convert chain makes the fragments non-rematerializable, so they
//   finally stay VGPR-resident (rounds 1-3: plain fp32 loads always got
//   re-sunk into the loop). Wave w owns output tiles {w, w+8} => af and ac
//   on the same lane, zero shuffles. h: 256B LDS row, broadcast reads.

#define LSTM_B 64
#define LSTM_E 128
#define LSTM_H 128
#define ROWW   256           // E+H, weight row width
#define TSTRIDE (2*LSTM_B*LSTM_H)   // floats per timestep in pre buffer

typedef __attribute__((ext_vector_type(8))) short bf16x8;
typedef __attribute__((ext_vector_type(4))) float f32x4;

__device__ __forceinline__ float fast_rcp(float x) {
    return __builtin_amdgcn_rcpf(x);
}
__device__ __forceinline__ float sigmoidf_(float x) {
    return fast_rcp(1.0f + __expf(-x));
}
__device__ __forceinline__ float tanh_fast(float x) {
    float ax = fabsf(x);
    float t = __expf(-2.0f * ax);          // in (0,1], no overflow
    float r = (1.0f - t) * fast_rcp(1.0f + t);
    return copysignf(r, x);
}
__device__ __forceinline__ short f2bf(float f) {   // round-to-nearest-even
    union { float f; unsigned u; } v; v.f = f;
    unsigned r = (v.u + 0x7FFFu + ((v.u >> 16) & 1u)) >> 16;
    return (short)r;
}
__device__ __forceinline__ float bf2f(short s) {
    union { unsigned u; float f; } v; v.u = ((unsigned)(unsigned short)s) << 16;
    return v.f;
}

// ---------------- Phase A: input projections for both gates ----------------
__global__ __launch_bounds__(256) void lstm_phaseA(
    const int* __restrict__ x, const float* __restrict__ emb,
    const float* __restrict__ Wf, const float* __restrict__ bf,
    const float* __restrict__ Wc, const float* __restrict__ bc,
    float* __restrict__ pre, int t0, int S)
{
    __shared__ __align__(16) float emb_s[16][LSTM_E];
    __shared__ int idx_s[16];

    const int tile = blockIdx.x;
    const int t  = t0 + (tile >> 2);
    const int b0 = (tile & 3) << 4;
    const int tid = threadIdx.x;

    if (tid < 16) idx_s[tid] = x[(size_t)(b0 + tid) * S + t];
    __syncthreads();
    {
        const int r  = tid >> 4;
        const int cp = (tid & 15) << 3;
        const float* src = emb + (size_t)idx_s[r] * LSTM_E + cp;
        float4 v0 = *(const float4*)src;
        float4 v1 = *(const float4*)(src + 4);
        *(float4*)&emb_s[r][cp]     = v0;
        *(float4*)&emb_s[r][cp + 4] = v1;
    }
    __syncthreads();

    const int g = tid >> 7, j = tid & 127;
    const float* Wrow = (g ? Wc : Wf) + (size_t)j * ROWW;
    const float bias  = (g ? bc : bf)[j];

    float acc[16];
#pragma unroll
    for (int b = 0; b < 16; ++b) acc[b] = bias;

    for (int kc = 0; kc < LSTM_E; kc += 16) {
        float4 wv[4];
#pragma unroll
        for (int i = 0; i < 4; ++i) wv[i] = *(const float4*)(Wrow + kc + 4*i);
#pragma unroll
        for (int b = 0; b < 16; ++b) {
#pragma unroll
            for (int i = 0; i < 4; ++i) {
                float4 ev = *(const float4*)&emb_s[b][kc + 4*i];
                acc[b] += ev.x*wv[i].x + ev.y*wv[i].y + ev.z*wv[i].z + ev.w*wv[i].w;
            }
        }
    }

    float* dst = pre + ((size_t)(t - t0) * 2 + g) * (LSTM_B * LSTM_H)
                     + (size_t)b0 * LSTM_H + j;
#pragma unroll
    for (int b = 0; b < 16; ++b) dst[(size_t)b * LSTM_H] = acc[b];
}

// ---------------- Phase B: the recurrence (MFMA) ----------------
// 64 blocks (1 batch each), 512 threads = 8 waves.
// Wave w, lane l: output j = 16*w + (l&15); gate-f tile = w, gate-c tile = w+8.
// B-frag (W, K=32 x N=16): lane l -> col n=l&15, k = 32*ks + 8*(l>>4) + e.
// A-frag (h, M=16 x K=32): lane l -> row m=l&15 (only m=0 real), same k;
//   all lanes read the row-0 bytes -> 4-address wave broadcast, conflict-free.
__global__ __launch_bounds__(512, 2) void lstm_phaseB(
    const float* __restrict__ Wf, const float* __restrict__ Wc,
    const float* __restrict__ Wfc, const float* __restrict__ bfc,
    const float* __restrict__ pre, float* __restrict__ state,
    float* __restrict__ out, int t0, int t1, int S)
{
    __shared__ __align__(16) short h_s[2][LSTM_H];   // bf16 h, double-buffered
    __shared__ float red_s[LSTM_H];

    const int b    = blockIdx.x;
    const int tid  = threadIdx.x;
    const int lane = tid & 63;
    const int w    = tid >> 6;          // wave 0..7
    const int jj   = 16 * w + (lane & 15);
    const int kb   = ((lane >> 4) & 3) * 8;   // k-sub-base within a kstep

    // ---- resident B-fragments: W h-part, bf16 hi/lo split ----
    bf16x8 bhiF[4], bloF[4], bhiC[4], bloC[4];
#pragma unroll
    for (int ks = 0; ks < 4; ++ks) {
        const float* rF = Wf + (size_t)jj * ROWW + LSTM_E + 32*ks + kb;
        const float* rC = Wc + (size_t)jj * ROWW + LSTM_E + 32*ks + kb;
        float4 f0 = *(const float4*)rF, f1 = *(const float4*)(rF + 4);
        float4 c0 = *(const float4*)rC, c1 = *(const float4*)(rC + 4);
        float ef[8] = {f0.x,f0.y,f0.z,f0.w,f1.x,f1.y,f1.z,f1.w};
        float ec[8] = {c0.x,c0.y,c0.z,c0.w,c1.x,c1.y,c1.z,c1.w};
#pragma unroll
        for (int e = 0; e < 8; ++e) {
            short h1 = f2bf(ef[e]);  bhiF[ks][e] = h1;  bloF[ks][e] = f2bf(ef[e] - bf2f(h1));
            short h2 = f2bf(ec[e]);  bhiC[ks][e] = h2;  bloC[ks][e] = f2bf(ec[e] - bf2f(h2));
        }
    }

    float c = 0.0f, h_last = 0.0f;
    if (t0 == 0) {
        if (tid < LSTM_H) h_s[0][tid] = 0;
    } else {
        if (tid < LSTM_H) h_s[0][tid] = f2bf(state[(size_t)b * LSTM_H + tid]);
        c = state[LSTM_B * LSTM_H + (size_t)b * LSTM_H + jj];
    }

    // pre stream, 2-deep prefetch (all lanes; lanes>=16 duplicate, coalesced)
    const float* prepF = pre + (size_t)b * LSTM_H + jj;        // [t][g=0][b][j]
    const float* prepC = prepF + LSTM_B * LSTM_H;              // g=1
    float pf0 = prepF[0], pc0 = prepC[0];
    float pf1 = 0.f, pc1 = 0.f;
    if (t1 - t0 > 1) { pf1 = prepF[TSTRIDE]; pc1 = prepC[TSTRIDE]; }
    __syncthreads();

    const f32x4 zz = {0.f, 0.f, 0.f, 0.f};
    int cur = 0;
    for (int t = t0; t < t1; ++t) {
        // A-fragments: 4 broadcast ds_read_b128 from the 256B h row
        const short* hb = &h_s[cur][0];
        bf16x8 a0 = *(const bf16x8*)(hb + 0*32 + kb);
        bf16x8 a1 = *(const bf16x8*)(hb + 1*32 + kb);
        bf16x8 a2 = *(const bf16x8*)(hb + 2*32 + kb);
        bf16x8 a3 = *(const bf16x8*)(hb + 3*32 + kb);

        float af = pf0, ac = pc0;
        pf0 = pf1; pc0 = pc1;
        if ((t - t0 + 2) < (t1 - t0)) {
            pf1 = prepF[(size_t)(t - t0 + 2) * TSTRIDE];
            pc1 = prepC[(size_t)(t - t0 + 2) * TSTRIDE];
        }

        // gate f: 4 independent depth-2 chains
        f32x4 f0 = __builtin_amdgcn_mfma_f32_16x16x32_bf16(a0, bhiF[0], zz, 0, 0, 0);
        f32x4 f1 = __builtin_amdgcn_mfma_f32_16x16x32_bf16(a1, bhiF[1], zz, 0, 0, 0);
        f32x4 f2 = __builtin_amdgcn_mfma_f32_16x16x32_bf16(a2, bhiF[2], zz, 0, 0, 0);
        f32x4 f3 = __builtin_amdgcn_mfma_f32_16x16x32_bf16(a3, bhiF[3], zz, 0, 0, 0);
        f0 = __builtin_amdgcn_mfma_f32_16x16x32_bf16(a0, bloF[0], f0, 0, 0, 0);
        f1 = __builtin_amdgcn_mfma_f32_16x16x32_bf16(a1, bloF[1], f1, 0, 0, 0);
        f2 = __builtin_amdgcn_mfma_f32_16x16x32_bf16(a2, bloF[2], f2, 0, 0, 0);
        f3 = __builtin_amdgcn_mfma_f32_16x16x32_bf16(a3, bloF[3], f3, 0, 0, 0);
        // gate c
        f32x4 g0 = __builtin_amdgcn_mfma_f32_16x16x32_bf16(a0, bhiC[0], zz, 0, 0, 0);
        f32x4 g1 = __builtin_amdgcn_mfma_f32_16x16x32_bf16(a1, bhiC[1], zz, 0, 0, 0);
        f32x4 g2 = __builtin_amdgcn_mfma_f32_16x16x32_bf16(a2, bhiC[2], zz, 0, 0, 0);
        f32x4 g3 = __builtin_amdgcn_mfma_f32_16x16x32_bf16(a3, bhiC[3], zz, 0, 0, 0);
        g0 = __builtin_amdgcn_mfma_f32_16x16x32_bf16(a0, bloC[0], g0, 0, 0, 0);
        g1 = __builtin_amdgcn_mfma_f32_16x16x32_bf16(a1, bloC[1], g1, 0, 0, 0);
        g2 = __builtin_amdgcn_mfma_f32_16x16x32_bf16(a2, bloC[2], g2, 0, 0, 0);
        g3 = __builtin_amdgcn_mfma_f32_16x16x32_bf16(a3, bloC[3], g3, 0, 0, 0);

        af += (f0[0] + f1[0]) + (f2[0] + f3[0]);   // C row 0 = the real batch
        ac += (g0[0] + g1[0]) + (g2[0] + g3[0]);

        float gg = sigmoidf_(af);        // shared gate (source bug: f==i==o)
        float ct = tanh_fast(ac);
        c = gg * (c + ct);
        float hn = gg * tanh_fast(c);
        h_last = hn;
        if (lane < 16) h_s[cur ^ 1][jj] = f2bf(hn);
        __syncthreads();                 // single barrier per step
        cur ^= 1;
    }

    if (t1 == S) {
        if (lane < 16) red_s[jj] = h_last * Wfc[jj];
        __syncthreads();
        if (tid < 64) {
            float s = red_s[tid] + red_s[tid + 64];
            s += __shfl_down(s, 32, 64);
            s += __shfl_down(s, 16, 64);
            s += __shfl_down(s, 8, 64);
            s += __shfl_down(s, 4, 64);
            s += __shfl_down(s, 2, 64);
            s += __shfl_down(s, 1, 64);
            if (tid == 0) out[b] = sigmoidf_(s + bfc[0]);
        }
    } else {
        if (lane < 16) {
            state[(size_t)b * LSTM_H + jj] = h_last;
            state[LSTM_B * LSTM_H + (size_t)b * LSTM_H + jj] = c;
        }
    }
}

extern "C" void kernel_launch(void* const* d_in, const int* in_sizes, int n_in,
                              void* d_out, int out_size, void* d_ws, size_t ws_size,
                              hipStream_t stream) {
    const int*   x   = (const int*)d_in[0];
    const float* emb = (const float*)d_in[1];
    const float* Wf  = (const float*)d_in[2];
    const float* bf  = (const float*)d_in[3];
    const float* Wc  = (const float*)d_in[4];
    const float* bc  = (const float*)d_in[5];
    const float* Wfc = (const float*)d_in[6];
    const float* bfc = (const float*)d_in[7];
    float* out = (float*)d_out;

    const int S = in_sizes[0] / LSTM_B;           // 2048

    float* state = (float*)d_ws;                              // h[64][128], c[64][128]
    float* pre   = state + (size_t)2 * LSTM_B * LSTM_H;       // + 64KB

    const size_t state_bytes = (size_t)2 * LSTM_B * LSTM_H * sizeof(float);
    const size_t per_t_bytes = (size_t)TSTRIDE * sizeof(float);   // 64 KB per step
    size_t avail = (ws_size > state_bytes) ? (ws_size - state_bytes) : 0;
    int CH = (int)(avail / per_t_bytes);
    if (CH > S) CH = S;
    if (CH < 1) CH = 1;   // requires ws_size >= 128KB + state

    for (int t0 = 0; t0 < S; t0 += CH) {
        const int t1 = (t0 + CH < S) ? (t0 + CH) : S;
        lstm_phaseA<<<(t1 - t0) * 4, 256, 0, stream>>>(x, emb, Wf, bf, Wc, bc,
                                                       pre, t0, S);
        lstm_phaseB<<<LSTM_B, 512, 0, stream>>>(Wf, Wc, Wfc, bfc, pre, state,
                                                out, t0, t1, S);
    }
}